// Round 14
// baseline (105.668 us; speedup 1.0000x reference)
//
#include <hip/hip_runtime.h>

namespace {

constexpr int T   = 30;
constexpr int C   = 4;
constexpr int HW  = 256 * 256;
constexpr int B   = 8;
constexpr int CHW = C * HW;

typedef _Float16 f16x2 __attribute__((ext_vector_type(2)));

__device__ __forceinline__ void scan_store(const float (&v)[T],
                                           const f16x2 (&fr)[T / 2],
                                           unsigned vis, bool none,
                                           float nanv, float* __restrict__ ob)
{
    // backward value-scan; nv packed f16x2 (compile-time indexed)
    f16x2 nvp[T / 2];
    {
        float run = 0.0f;
#pragma unroll
        for (int t = T - 1; t >= 0; --t) {
            run = ((vis >> t) & 1u) ? v[t] : run;
            if (t & 1) nvp[t >> 1].y = (_Float16)run;
            else       nvp[t >> 1].x = (_Float16)run;
        }
    }
    // forward scan (rl = nv[t] at visible t) + blend + nt store
    {
        float rl = 0.0f;
#pragma unroll
        for (int t = 0; t < T; ++t) {
            const float nv = (t & 1) ? (float)nvp[t >> 1].y
                                     : (float)nvp[t >> 1].x;
            rl = ((vis >> t) & 1u) ? nv : rl;
            const float f  = (t & 1) ? (float)fr[t >> 1].y
                                     : (float)fr[t >> 1].x;
            const float res = fmaf(f, nv - rl, rl);
            __builtin_nontemporal_store(none ? nanv : res,
                                        &ob[(size_t)t * CHW]);
        }
    }
}

// R13 base (cached loads, nt stores, batched loads + sched_barrier(0),
// f16x2 scan arrays, (4,4) = proven spill-free pin). Change: depth-1
// software pipeline over channels -- ch(c+1)'s 30 loads issue BEFORE
// ch c's scan+store, so every load batch has a full scan phase between
// issue and drain. Zero interior exposed-latency windows (R13 had 1,
// R10 had 3). Ping-pong va/vb named arrays, fully unrolled -> all
// compile-time indexing. Peak live ~90 VGPR fits the 128-reg budget.
__global__ __attribute__((amdgpu_flat_work_group_size(256, 256)))
           __attribute__((amdgpu_waves_per_eu(4, 4)))
void interp_kernel(
    const float* __restrict__ images,
    const float* __restrict__ mask,
    const float* __restrict__ days,
    float* __restrict__ out)
{
    __shared__ float s_day[T];
    const int tid = threadIdx.x;
    const int b   = blockIdx.x >> 8;            // 256 blocks per batch image
    if (tid < T) s_day[tid] = days[b * T + tid];
    __syncthreads();

    const int hw = ((blockIdx.x & 255) << 8) | tid;

    const size_t pixBase = (size_t)b * T * CHW + hw;
    const float* ib = images + pixBase;
    float*       ob = out    + pixBase;

    // ---- visibility bitmask: 30 batched cached loads ----
    const float* mbase = mask + (size_t)b * T * HW + hw;
    unsigned vis = 0u;
    {
        float mv[T];
#pragma unroll
        for (int t = 0; t < T; ++t) mv[t] = mbase[(size_t)t * HW];
        __builtin_amdgcn_sched_barrier(0);
#pragma unroll
        for (int t = 0; t < T; ++t) vis |= (mv[t] == 0.0f ? 1u : 0u) << t;
    }

    // ---- fr[]: backward day-of-next-visible scan (f16 exact: integer
    //      days), then transformed in place to frac on the forward pass ----
    f16x2 fr[T / 2];
    {
        float run = 0.0f;
#pragma unroll
        for (int t = T - 1; t >= 0; --t) {
            run = ((vis >> t) & 1u) ? s_day[t] : run;
            if (t & 1) fr[t >> 1].y = (_Float16)run;
            else       fr[t >> 1].x = (_Float16)run;
        }
        float dl = 0.0f;
#pragma unroll
        for (int t = 0; t < T; ++t) {
            const float d = s_day[t];
            dl = ((vis >> t) & 1u) ? d : dl;
            const float dn = (t & 1) ? (float)fr[t >> 1].y
                                     : (float)fr[t >> 1].x;
            float den = dn - dl;
            den = (den == 0.0f) ? 1.0f : den;
            float f = (d - dl) / den;
            const bool lv_ok = (vis & ((1u << (t + 1)) - 1u)) != 0u;
            const bool nv_ok = (vis >> t) != 0u;
            // visible/only_last/none -> 0 ; only_next -> 1 (rl==0 => img_next)
            f = (lv_ok && nv_ok) ? f : (nv_ok ? 1.0f : 0.0f);
            if (t & 1) fr[t >> 1].y = (_Float16)f;
            else       fr[t >> 1].x = (_Float16)f;
        }
    }

    const bool  none = (vis == 0u);
    const float nanv = __int_as_float(0x7fc00000);

    float va[T], vb[T];

    // prologue: ch0 loads
#pragma unroll
    for (int t = 0; t < T; ++t) va[t] = ib[(size_t)t * CHW];
    __builtin_amdgcn_sched_barrier(0);

    // ch1 loads in flight, scan ch0
#pragma unroll
    for (int t = 0; t < T; ++t) vb[t] = ib[(size_t)t * CHW + HW];
    __builtin_amdgcn_sched_barrier(0);
    scan_store(va, fr, vis, none, nanv, ob);
    __builtin_amdgcn_sched_barrier(0);

    // ch2 loads in flight, scan ch1
#pragma unroll
    for (int t = 0; t < T; ++t) va[t] = ib[(size_t)t * CHW + 2 * HW];
    __builtin_amdgcn_sched_barrier(0);
    scan_store(vb, fr, vis, none, nanv, ob + HW);
    __builtin_amdgcn_sched_barrier(0);

    // ch3 loads in flight, scan ch2
#pragma unroll
    for (int t = 0; t < T; ++t) vb[t] = ib[(size_t)t * CHW + 3 * HW];
    __builtin_amdgcn_sched_barrier(0);
    scan_store(va, fr, vis, none, nanv, ob + 2 * HW);
    __builtin_amdgcn_sched_barrier(0);

    // epilogue: scan ch3
    scan_store(vb, fr, vis, none, nanv, ob + 3 * HW);
}

} // namespace

extern "C" void kernel_launch(void* const* d_in, const int* in_sizes, int n_in,
                              void* d_out, int out_size, void* d_ws, size_t ws_size,
                              hipStream_t stream)
{
    const float* images = (const float*)d_in[0];
    const float* mask   = (const float*)d_in[1];
    const float* days   = (const float*)d_in[2];
    float* out          = (float*)d_out;

    const int nPix = B * HW;                 // one thread per (b, h, w)
    dim3 grid(nPix / 256), block(256);
    hipLaunchKernelGGL(interp_kernel, grid, block, 0, stream,
                       images, mask, days, out);
}